// Round 1
// baseline (1918.493 us; speedup 1.0000x reference)
//
#include <hip/hip_runtime.h>
#include <hip/hip_bf16.h>
#include <cstddef>

#define N_USERS 50000
#define N_ITEMS 10000
#define N_NODES 100000
#define EMB 64
#define NNZ_E 1600000
#define VIS_DIM 2048
#define TXT_DIM 300

// ---------------------------------------------------------------------------
// Tiled fp32 GEMM: C[M,N] = act(A[M,K] @ W[N,K]^T + bias[N]), optional ReLU.
// 64x64 block tile, BK=16, 256 threads, 4x4 per-thread microtile.
// ---------------------------------------------------------------------------
#define TS 64
#define KS 16

__global__ __launch_bounds__(256) void gemm_at(
    const float* __restrict__ A, const float* __restrict__ W,
    const float* __restrict__ bias, float* __restrict__ C,
    int M, int N, int K, int relu)
{
    __shared__ float As[KS][TS + 4];
    __shared__ float Bs[KS][TS + 4];
    const int t   = threadIdx.x;
    const int m0  = blockIdx.y * TS;
    const int n0  = blockIdx.x * TS;
    const int tx  = t & 15, ty = t >> 4;
    const int ldr = t >> 2;          // 0..63: row within tile
    const int ldc = (t & 3) * 4;     // k offset: 0,4,8,12

    float acc[4][4] = {};

    for (int k0 = 0; k0 < K; k0 += KS) {
        // ---- stage A tile (As[k][m]) ----
        {
            int m = m0 + ldr;
            float v0 = 0.f, v1 = 0.f, v2 = 0.f, v3 = 0.f;
            if (m < M) {
                const float* p = A + (size_t)m * K + k0 + ldc;
                if (k0 + ldc + 3 < K) {
                    float4 v = *(const float4*)p;
                    v0 = v.x; v1 = v.y; v2 = v.z; v3 = v.w;
                } else {
                    if (k0 + ldc + 0 < K) v0 = p[0];
                    if (k0 + ldc + 1 < K) v1 = p[1];
                    if (k0 + ldc + 2 < K) v2 = p[2];
                    if (k0 + ldc + 3 < K) v3 = p[3];
                }
            }
            As[ldc + 0][ldr] = v0; As[ldc + 1][ldr] = v1;
            As[ldc + 2][ldr] = v2; As[ldc + 3][ldr] = v3;
        }
        // ---- stage W tile (Bs[k][n]) ----
        {
            int n = n0 + ldr;
            float v0 = 0.f, v1 = 0.f, v2 = 0.f, v3 = 0.f;
            if (n < N) {
                const float* p = W + (size_t)n * K + k0 + ldc;
                if (k0 + ldc + 3 < K) {
                    float4 v = *(const float4*)p;
                    v0 = v.x; v1 = v.y; v2 = v.z; v3 = v.w;
                } else {
                    if (k0 + ldc + 0 < K) v0 = p[0];
                    if (k0 + ldc + 1 < K) v1 = p[1];
                    if (k0 + ldc + 2 < K) v2 = p[2];
                    if (k0 + ldc + 3 < K) v3 = p[3];
                }
            }
            Bs[ldc + 0][ldr] = v0; Bs[ldc + 1][ldr] = v1;
            Bs[ldc + 2][ldr] = v2; Bs[ldc + 3][ldr] = v3;
        }
        __syncthreads();

        #pragma unroll
        for (int k = 0; k < KS; k++) {
            float a0 = As[k][ty * 4 + 0], a1 = As[k][ty * 4 + 1];
            float a2 = As[k][ty * 4 + 2], a3 = As[k][ty * 4 + 3];
            float b0 = Bs[k][tx * 4 + 0], b1 = Bs[k][tx * 4 + 1];
            float b2 = Bs[k][tx * 4 + 2], b3 = Bs[k][tx * 4 + 3];
            acc[0][0] += a0 * b0; acc[0][1] += a0 * b1; acc[0][2] += a0 * b2; acc[0][3] += a0 * b3;
            acc[1][0] += a1 * b0; acc[1][1] += a1 * b1; acc[1][2] += a1 * b2; acc[1][3] += a1 * b3;
            acc[2][0] += a2 * b0; acc[2][1] += a2 * b1; acc[2][2] += a2 * b2; acc[2][3] += a2 * b3;
            acc[3][0] += a3 * b0; acc[3][1] += a3 * b1; acc[3][2] += a3 * b2; acc[3][3] += a3 * b3;
        }
        __syncthreads();
    }

    #pragma unroll
    for (int i = 0; i < 4; i++) {
        int m = m0 + ty * 4 + i;
        if (m >= M) continue;
        #pragma unroll
        for (int j = 0; j < 4; j++) {
            int n = n0 + tx * 4 + j;
            if (n >= N) continue;
            float v = acc[i][j] + bias[n];
            if (relu) v = fmaxf(v, 0.f);
            C[(size_t)m * N + n] = v;
        }
    }
}

// ---------------------------------------------------------------------------
// Transpose weight W[64,K] -> wT[K,64]  (wT[k*64+d] = W[d*K+k])
// ---------------------------------------------------------------------------
__global__ void transp64(const float* __restrict__ W, float* __restrict__ wT, int K)
{
    int i = blockIdx.x * 256 + threadIdx.x;
    if (i >= 64 * K) return;
    int d = i / K, k = i - d * K;
    wT[k * 64 + d] = W[i];
}

// ---------------------------------------------------------------------------
// out[m,0:64] (+)= act-free: in_scale * (in[m,:K] @ wT[K,64]) + bias
// block = 256 threads = 4 rows x 64 dims
// ---------------------------------------------------------------------------
__global__ __launch_bounds__(256) void linear64(
    const float* __restrict__ in, const float* __restrict__ wT,
    const float* __restrict__ bias, float* __restrict__ out,
    int M, int K, float in_scale, int add)
{
    int t = threadIdx.x;
    int d = t & 63;
    int m = blockIdx.x * 4 + (t >> 6);
    if (m >= M) return;
    const float* x = in + (size_t)m * K;
    float acc = 0.f;
    for (int k = 0; k < K; k++) acc += x[k] * wT[k * 64 + d];
    float r = acc * in_scale + bias[d];
    if (add) out[(size_t)m * 64 + d] += r;
    else     out[(size_t)m * 64 + d]  = r;
}

// ---------------------------------------------------------------------------
// Build ego: non-item rows copied from embedding into cur0; every row's
// cur0 copied into out[:, 0:64].  (item rows of cur0 were already written
// by the fused-item linear.)
// ---------------------------------------------------------------------------
__global__ void ego_fill(const float* __restrict__ emb, float* __restrict__ cur0,
                         float* __restrict__ out_full)
{
    int tid = blockIdx.x * 256 + threadIdx.x;
    if (tid >= N_NODES * EMB) return;
    int m = tid >> 6, d = tid & 63;
    float v;
    if (m < N_USERS || m >= N_USERS + N_ITEMS) {
        v = emb[tid];
        cur0[tid] = v;
    } else {
        v = cur0[tid];
    }
    out_full[(size_t)m * 192 + d] = v;
}

// ---------------------------------------------------------------------------
// SpMM scatter: nb[row[e], d] += val[e] * cur[col[e], d]   (atomic)
// block = 256 threads = 4 edges x 64 dims
// ---------------------------------------------------------------------------
__global__ __launch_bounds__(256) void spmm_atomic(
    const int* __restrict__ row, const int* __restrict__ col,
    const float* __restrict__ val, const float* __restrict__ cur,
    float* __restrict__ nb, int nnz)
{
    int t = threadIdx.x;
    int e = blockIdx.x * 4 + (t >> 6);
    int d = t & 63;
    if (e >= nnz) return;
    float v = val[e];
    int r = row[e], c = col[e];
    atomicAdd(&nb[(size_t)r * 64 + d], v * cur[(size_t)c * 64 + d]);
}

// ---------------------------------------------------------------------------
// cur_next[m,d] = leaky_relu( bias[d] + sum_k cur[m,k]*wT[k,d]
//                                     + sum_k nb[m,k]*wT[64+k,d], 0.01 )
// wT is the transposed Wc: wT[k*64+d] = Wc[d*128+k], k in [0,128)
// ---------------------------------------------------------------------------
__global__ __launch_bounds__(256) void concat_lin(
    const float* __restrict__ cur, const float* __restrict__ nb,
    const float* __restrict__ wT, const float* __restrict__ bias,
    float* __restrict__ out_cur, float* __restrict__ out_full, int col_off)
{
    int t = threadIdx.x;
    int d = t & 63;
    int m = blockIdx.x * 4 + (t >> 6);
    if (m >= N_NODES) return;
    const float* x1 = cur + (size_t)m * 64;
    const float* x2 = nb  + (size_t)m * 64;
    float acc = bias[d];
    #pragma unroll 4
    for (int k = 0; k < 64; k++) acc += x1[k] * wT[k * 64 + d];
    #pragma unroll 4
    for (int k = 0; k < 64; k++) acc += x2[k] * wT[(64 + k) * 64 + d];
    float r = (acc > 0.f) ? acc : 0.01f * acc;
    if (out_cur) out_cur[(size_t)m * 64 + d] = r;
    out_full[(size_t)m * 192 + col_off + d] = r;
}

// ---------------------------------------------------------------------------
extern "C" void kernel_launch(void* const* d_in, const int* in_sizes, int n_in,
                              void* d_out, int out_size, void* d_ws, size_t ws_size,
                              hipStream_t stream)
{
    const int*   adj_row = (const int*)  d_in[0];
    const int*   adj_col = (const int*)  d_in[1];
    const float* adj_val = (const float*)d_in[2];
    const float* emb     = (const float*)d_in[3];
    const float* visf    = (const float*)d_in[4];
    const float* txtf    = (const float*)d_in[5];
    const float* Wv1 = (const float*)d_in[6];  const float* bv1 = (const float*)d_in[7];
    const float* Wv2 = (const float*)d_in[8];  const float* bv2 = (const float*)d_in[9];
    const float* Wt1 = (const float*)d_in[10]; const float* bt1 = (const float*)d_in[11];
    const float* Wt2 = (const float*)d_in[12]; const float* bt2 = (const float*)d_in[13];
    const float* Wd  = (const float*)d_in[14]; const float* bd  = (const float*)d_in[15];
    const float* Wc0 = (const float*)d_in[16]; const float* bc0 = (const float*)d_in[17];
    const float* Wc1 = (const float*)d_in[18]; const float* bc1 = (const float*)d_in[19];

    float* out = (float*)d_out;
    float* ws  = (float*)d_ws;

    // workspace layout (floats)
    float* H1v  = ws + 0;                       // 10000*512 = 5,120,000
    float* H1t  = ws + 5120000;                 // 10000*256 = 2,560,000
    float* nb   = ws + 0;                       // 6,400,000 (reuses H1v/H1t after use)
    float* s    = ws + 7680000;                 //   640,000
    float* cur0 = ws + 8320000;                 // 6,400,000
    float* cur1 = ws + 14720000;                // 6,400,000
    float* wv2T = ws + 21120000;                // 512*64 = 32768
    float* wt2T = wv2T + 32768;                 // 256*64 = 16384
    float* wdT  = wt2T + 16384;                 //  64*64 =  4096
    float* wc0T = wdT  + 4096;                  // 128*64 =  8192
    float* wc1T = wc0T + 8192;                  // 128*64 =  8192

    // ---- weight transposes (tiny) ----
    transp64<<<(64 * 512 + 255) / 256, 256, 0, stream>>>(Wv2, wv2T, 512);
    transp64<<<(64 * 256 + 255) / 256, 256, 0, stream>>>(Wt2, wt2T, 256);
    transp64<<<(64 * 64  + 255) / 256, 256, 0, stream>>>(Wd,  wdT,  64);
    transp64<<<(64 * 128 + 255) / 256, 256, 0, stream>>>(Wc0, wc0T, 128);
    transp64<<<(64 * 128 + 255) / 256, 256, 0, stream>>>(Wc1, wc1T, 128);

    // ---- item MLP layer 1 (the big GEMMs) ----
    {
        dim3 g(512 / TS, (N_ITEMS + TS - 1) / TS);
        gemm_at<<<g, 256, 0, stream>>>(visf, Wv1, bv1, H1v, N_ITEMS, 512, VIS_DIM, 1);
    }
    {
        dim3 g(256 / TS, (N_ITEMS + TS - 1) / TS);
        gemm_at<<<g, 256, 0, stream>>>(txtf, Wt1, bt1, H1t, N_ITEMS, 256, TXT_DIM, 1);
    }

    // ---- layer 2 + shared Wd:  fused = (0.5*(vis2+txt2)) @ Wd^T + bd ----
    linear64<<<(N_ITEMS + 3) / 4, 256, 0, stream>>>(H1v, wv2T, bv2, s, N_ITEMS, 512, 1.0f, 0);
    linear64<<<(N_ITEMS + 3) / 4, 256, 0, stream>>>(H1t, wt2T, bt2, s, N_ITEMS, 256, 1.0f, 1);
    linear64<<<(N_ITEMS + 3) / 4, 256, 0, stream>>>(s, wdT, bd, cur0 + (size_t)N_USERS * 64,
                                                    N_ITEMS, 64, 0.5f, 0);

    // ---- assemble ego, write out[:, 0:64] ----
    ego_fill<<<(N_NODES * EMB + 255) / 256, 256, 0, stream>>>(emb, cur0, out);

    // ---- propagation layer 1 ----
    hipMemsetAsync(nb, 0, (size_t)N_NODES * 64 * sizeof(float), stream);
    spmm_atomic<<<(NNZ_E + 3) / 4, 256, 0, stream>>>(adj_row, adj_col, adj_val, cur0, nb, NNZ_E);
    concat_lin<<<(N_NODES + 3) / 4, 256, 0, stream>>>(cur0, nb, wc0T, bc0, cur1, out, 64);

    // ---- propagation layer 2 ----
    hipMemsetAsync(nb, 0, (size_t)N_NODES * 64 * sizeof(float), stream);
    spmm_atomic<<<(NNZ_E + 3) / 4, 256, 0, stream>>>(adj_row, adj_col, adj_val, cur1, nb, NNZ_E);
    concat_lin<<<(N_NODES + 3) / 4, 256, 0, stream>>>(cur1, nb, wc1T, bc1, nullptr, out, 128);
}

// Round 2
// 1701.031 us; speedup vs baseline: 1.1278x; 1.1278x over previous
//
#include <hip/hip_runtime.h>
#include <hip/hip_bf16.h>
#include <cstddef>

#define N_USERS 50000
#define N_ITEMS 10000
#define N_NODES 100000
#define EMB 64
#define NNZ_E 1600000
#define VIS_DIM 2048
#define TXT_DIM 300

// ---------------------------------------------------------------------------
// Tiled fp32 GEMM: C[M,N] = act(A[M,K] @ W[N,K]^T + bias[N]), optional ReLU.
// 64x64 block tile, BK=16, 256 threads, 4x4 per-thread microtile.
// ---------------------------------------------------------------------------
#define TS 64
#define KS 16

__global__ __launch_bounds__(256) void gemm_at(
    const float* __restrict__ A, const float* __restrict__ W,
    const float* __restrict__ bias, float* __restrict__ C,
    int M, int N, int K, int relu)
{
    __shared__ float As[KS][TS + 4];
    __shared__ float Bs[KS][TS + 4];
    const int t   = threadIdx.x;
    const int m0  = blockIdx.y * TS;
    const int n0  = blockIdx.x * TS;
    const int tx  = t & 15, ty = t >> 4;
    const int ldr = t >> 2;          // 0..63: row within tile
    const int ldc = (t & 3) * 4;     // k offset: 0,4,8,12

    float acc[4][4] = {};

    for (int k0 = 0; k0 < K; k0 += KS) {
        {
            int m = m0 + ldr;
            float v0 = 0.f, v1 = 0.f, v2 = 0.f, v3 = 0.f;
            if (m < M) {
                const float* p = A + (size_t)m * K + k0 + ldc;
                if (k0 + ldc + 3 < K) {
                    float4 v = *(const float4*)p;
                    v0 = v.x; v1 = v.y; v2 = v.z; v3 = v.w;
                } else {
                    if (k0 + ldc + 0 < K) v0 = p[0];
                    if (k0 + ldc + 1 < K) v1 = p[1];
                    if (k0 + ldc + 2 < K) v2 = p[2];
                    if (k0 + ldc + 3 < K) v3 = p[3];
                }
            }
            As[ldc + 0][ldr] = v0; As[ldc + 1][ldr] = v1;
            As[ldc + 2][ldr] = v2; As[ldc + 3][ldr] = v3;
        }
        {
            int n = n0 + ldr;
            float v0 = 0.f, v1 = 0.f, v2 = 0.f, v3 = 0.f;
            if (n < N) {
                const float* p = W + (size_t)n * K + k0 + ldc;
                if (k0 + ldc + 3 < K) {
                    float4 v = *(const float4*)p;
                    v0 = v.x; v1 = v.y; v2 = v.z; v3 = v.w;
                } else {
                    if (k0 + ldc + 0 < K) v0 = p[0];
                    if (k0 + ldc + 1 < K) v1 = p[1];
                    if (k0 + ldc + 2 < K) v2 = p[2];
                    if (k0 + ldc + 3 < K) v3 = p[3];
                }
            }
            Bs[ldc + 0][ldr] = v0; Bs[ldc + 1][ldr] = v1;
            Bs[ldc + 2][ldr] = v2; Bs[ldc + 3][ldr] = v3;
        }
        __syncthreads();

        #pragma unroll
        for (int k = 0; k < KS; k++) {
            float a0 = As[k][ty * 4 + 0], a1 = As[k][ty * 4 + 1];
            float a2 = As[k][ty * 4 + 2], a3 = As[k][ty * 4 + 3];
            float b0 = Bs[k][tx * 4 + 0], b1 = Bs[k][tx * 4 + 1];
            float b2 = Bs[k][tx * 4 + 2], b3 = Bs[k][tx * 4 + 3];
            acc[0][0] += a0 * b0; acc[0][1] += a0 * b1; acc[0][2] += a0 * b2; acc[0][3] += a0 * b3;
            acc[1][0] += a1 * b0; acc[1][1] += a1 * b1; acc[1][2] += a1 * b2; acc[1][3] += a1 * b3;
            acc[2][0] += a2 * b0; acc[2][1] += a2 * b1; acc[2][2] += a2 * b2; acc[2][3] += a2 * b3;
            acc[3][0] += a3 * b0; acc[3][1] += a3 * b1; acc[3][2] += a3 * b2; acc[3][3] += a3 * b3;
        }
        __syncthreads();
    }

    #pragma unroll
    for (int i = 0; i < 4; i++) {
        int m = m0 + ty * 4 + i;
        if (m >= M) continue;
        #pragma unroll
        for (int j = 0; j < 4; j++) {
            int n = n0 + tx * 4 + j;
            if (n >= N) continue;
            float v = acc[i][j] + bias[n];
            if (relu) v = fmaxf(v, 0.f);
            C[(size_t)m * N + n] = v;
        }
    }
}

// ---------------------------------------------------------------------------
__global__ void transp64(const float* __restrict__ W, float* __restrict__ wT, int K)
{
    int i = blockIdx.x * 256 + threadIdx.x;
    if (i >= 64 * K) return;
    int d = i / K, k = i - d * K;
    wT[k * 64 + d] = W[i];
}

// ---------------------------------------------------------------------------
__global__ __launch_bounds__(256) void linear64(
    const float* __restrict__ in, const float* __restrict__ wT,
    const float* __restrict__ bias, float* __restrict__ out,
    int M, int K, float in_scale, int add)
{
    int t = threadIdx.x;
    int d = t & 63;
    int m = blockIdx.x * 4 + (t >> 6);
    if (m >= M) return;
    const float* x = in + (size_t)m * K;
    float acc = 0.f;
    for (int k = 0; k < K; k++) acc += x[k] * wT[k * 64 + d];
    float r = acc * in_scale + bias[d];
    if (add) out[(size_t)m * 64 + d] += r;
    else     out[(size_t)m * 64 + d]  = r;
}

// ---------------------------------------------------------------------------
__global__ void ego_fill(const float* __restrict__ emb, float* __restrict__ cur0,
                         float* __restrict__ out_full)
{
    int tid = blockIdx.x * 256 + threadIdx.x;
    if (tid >= N_NODES * EMB) return;
    int m = tid >> 6, d = tid & 63;
    float v;
    if (m < N_USERS || m >= N_USERS + N_ITEMS) {
        v = emb[tid];
        cur0[tid] = v;
    } else {
        v = cur0[tid];
    }
    out_full[(size_t)m * 192 + d] = v;
}

// ---------------------------------------------------------------------------
// CSR build: histogram -> exclusive scan (3 kernels) -> stable-ish scatter
// ---------------------------------------------------------------------------
__global__ __launch_bounds__(256) void hist_rows(
    const int* __restrict__ row, int* __restrict__ cnt, int nnz)
{
    int e = blockIdx.x * 256 + threadIdx.x;
    if (e >= nnz) return;
    atomicAdd(&cnt[row[e]], 1);
}

// per-block (1024 elems) exclusive scan, in place; block sums out.
__global__ __launch_bounds__(256) void scan1(int* __restrict__ cnt,
                                             int* __restrict__ bsum, int n)
{
    __shared__ int part[256];
    int t = threadIdx.x;
    int base = blockIdx.x * 1024 + t * 4;
    int v0 = 0, v1 = 0, v2 = 0, v3 = 0;
    if (base + 0 < n) v0 = cnt[base + 0];
    if (base + 1 < n) v1 = cnt[base + 1];
    if (base + 2 < n) v2 = cnt[base + 2];
    if (base + 3 < n) v3 = cnt[base + 3];
    int s = v0 + v1 + v2 + v3;
    part[t] = s;
    __syncthreads();
    for (int off = 1; off < 256; off <<= 1) {
        int x = (t >= off) ? part[t - off] : 0;
        __syncthreads();
        part[t] += x;
        __syncthreads();
    }
    int excl = part[t] - s;
    if (t == 255) bsum[blockIdx.x] = part[t];
    if (base + 0 < n) cnt[base + 0] = excl;
    if (base + 1 < n) cnt[base + 1] = excl + v0;
    if (base + 2 < n) cnt[base + 2] = excl + v0 + v1;
    if (base + 3 < n) cnt[base + 3] = excl + v0 + v1 + v2;
}

__global__ void scan2(int* __restrict__ bsum, int nb)
{
    if (threadIdx.x == 0 && blockIdx.x == 0) {
        int acc = 0;
        for (int i = 0; i < nb; i++) { int v = bsum[i]; bsum[i] = acc; acc += v; }
    }
}

__global__ __launch_bounds__(256) void scan3(
    const int* __restrict__ excl, const int* __restrict__ bsum,
    int* __restrict__ row_ptr, int* __restrict__ row_cur, int n, int nnz)
{
    int i = blockIdx.x * 256 + threadIdx.x;
    if (i > n) return;
    if (i == n) { row_ptr[n] = nnz; return; }
    int v = excl[i] + bsum[i >> 10];
    row_ptr[i] = v;
    row_cur[i] = v;
}

__global__ __launch_bounds__(256) void scatter_csr(
    const int* __restrict__ row, const int* __restrict__ col,
    const float* __restrict__ val, int* __restrict__ row_cur,
    int* __restrict__ col_s, float* __restrict__ val_s, int nnz)
{
    int e = blockIdx.x * 256 + threadIdx.x;
    if (e >= nnz) return;
    int r = row[e];
    int p = atomicAdd(&row_cur[r], 1);
    col_s[p] = col[e];
    val_s[p] = val[e];
}

// ---------------------------------------------------------------------------
// Gather SpMM: one wave per row. nb[m,d] = sum_{j in row m} val_s[j]*cur[col_s[j],d]
// No atomics, each output written exactly once.
// ---------------------------------------------------------------------------
__global__ __launch_bounds__(256) void spmm_gather(
    const int* __restrict__ row_ptr, const int* __restrict__ col_s,
    const float* __restrict__ val_s, const float* __restrict__ cur,
    float* __restrict__ nb)
{
    int t = threadIdx.x;
    int d = t & 63;
    int m = blockIdx.x * 4 + (t >> 6);
    if (m >= N_NODES) return;
    int beg = row_ptr[m], end = row_ptr[m + 1];
    float acc = 0.f;
    for (int j = beg; j < end; j++) {
        int   c = col_s[j];
        float v = val_s[j];
        acc += v * cur[(size_t)c * 64 + d];
    }
    nb[(size_t)m * 64 + d] = acc;
}

// ---------------------------------------------------------------------------
__global__ __launch_bounds__(256) void concat_lin(
    const float* __restrict__ cur, const float* __restrict__ nb,
    const float* __restrict__ wT, const float* __restrict__ bias,
    float* __restrict__ out_cur, float* __restrict__ out_full, int col_off)
{
    int t = threadIdx.x;
    int d = t & 63;
    int m = blockIdx.x * 4 + (t >> 6);
    if (m >= N_NODES) return;
    const float* x1 = cur + (size_t)m * 64;
    const float* x2 = nb  + (size_t)m * 64;
    float acc = bias[d];
    #pragma unroll 4
    for (int k = 0; k < 64; k++) acc += x1[k] * wT[k * 64 + d];
    #pragma unroll 4
    for (int k = 0; k < 64; k++) acc += x2[k] * wT[(64 + k) * 64 + d];
    float r = (acc > 0.f) ? acc : 0.01f * acc;
    if (out_cur) out_cur[(size_t)m * 64 + d] = r;
    out_full[(size_t)m * 192 + col_off + d] = r;
}

// ---------------------------------------------------------------------------
extern "C" void kernel_launch(void* const* d_in, const int* in_sizes, int n_in,
                              void* d_out, int out_size, void* d_ws, size_t ws_size,
                              hipStream_t stream)
{
    const int*   adj_row = (const int*)  d_in[0];
    const int*   adj_col = (const int*)  d_in[1];
    const float* adj_val = (const float*)d_in[2];
    const float* emb     = (const float*)d_in[3];
    const float* visf    = (const float*)d_in[4];
    const float* txtf    = (const float*)d_in[5];
    const float* Wv1 = (const float*)d_in[6];  const float* bv1 = (const float*)d_in[7];
    const float* Wv2 = (const float*)d_in[8];  const float* bv2 = (const float*)d_in[9];
    const float* Wt1 = (const float*)d_in[10]; const float* bt1 = (const float*)d_in[11];
    const float* Wt2 = (const float*)d_in[12]; const float* bt2 = (const float*)d_in[13];
    const float* Wd  = (const float*)d_in[14]; const float* bd  = (const float*)d_in[15];
    const float* Wc0 = (const float*)d_in[16]; const float* bc0 = (const float*)d_in[17];
    const float* Wc1 = (const float*)d_in[18]; const float* bc1 = (const float*)d_in[19];

    float* out = (float*)d_out;
    float* ws  = (float*)d_ws;

    // workspace layout (float offsets)
    float* H1v  = ws + 0;          // 10000*512          [dead after linear64 #1]
    float* H1t  = ws + 5120000;    // 10000*256          [dead after linear64 #2]
    float* nb   = ws + 0;          // 100000*64 (reuses H1v/H1t region)
    float* s    = ws + 7680000;    // 10000*64
    float* cur0 = ws + 8320000;    // 100000*64
    float* cur1 = ws + 14720000;   // 100000*64
    float* wv2T = ws + 21120000;   // 512*64
    float* wt2T = wv2T + 32768;    // 256*64
    float* wdT  = wt2T + 16384;    // 64*64
    float* wc0T = wdT  + 4096;     // 128*64
    float* wc1T = wc0T + 8192;     // 128*64
    // CSR scratch
    int*   col_s   = (int*)  (ws + 21200000);  // 1.6M
    float* val_s   =          ws + 22800000;   // 1.6M
    int*   row_ptr = (int*)  (ws + 24400000);  // 100001
    int*   row_cur = (int*)  (ws + 24510000);  // 100000
    int*   cnt     = (int*)  (ws + 24620000);  // 100000 (scanned in place)
    int*   bsum    = (int*)  (ws + 24730000);  // 98

    const int NBLK = (N_NODES + 1023) / 1024;  // 98

    // ---- weight transposes (tiny) ----
    transp64<<<(64 * 512 + 255) / 256, 256, 0, stream>>>(Wv2, wv2T, 512);
    transp64<<<(64 * 256 + 255) / 256, 256, 0, stream>>>(Wt2, wt2T, 256);
    transp64<<<(64 * 64  + 255) / 256, 256, 0, stream>>>(Wd,  wdT,  64);
    transp64<<<(64 * 128 + 255) / 256, 256, 0, stream>>>(Wc0, wc0T, 128);
    transp64<<<(64 * 128 + 255) / 256, 256, 0, stream>>>(Wc1, wc1T, 128);

    // ---- CSR build (reused for both propagation layers) ----
    hipMemsetAsync(cnt, 0, N_NODES * sizeof(int), stream);
    hist_rows<<<(NNZ_E + 255) / 256, 256, 0, stream>>>(adj_row, cnt, NNZ_E);
    scan1<<<NBLK, 256, 0, stream>>>(cnt, bsum, N_NODES);
    scan2<<<1, 64, 0, stream>>>(bsum, NBLK);
    scan3<<<(N_NODES + 256) / 256, 256, 0, stream>>>(cnt, bsum, row_ptr, row_cur,
                                                     N_NODES, NNZ_E);
    scatter_csr<<<(NNZ_E + 255) / 256, 256, 0, stream>>>(adj_row, adj_col, adj_val,
                                                         row_cur, col_s, val_s, NNZ_E);

    // ---- item MLP layer 1 (the big GEMMs) ----
    {
        dim3 g(512 / TS, (N_ITEMS + TS - 1) / TS);
        gemm_at<<<g, 256, 0, stream>>>(visf, Wv1, bv1, H1v, N_ITEMS, 512, VIS_DIM, 1);
    }
    {
        dim3 g(256 / TS, (N_ITEMS + TS - 1) / TS);
        gemm_at<<<g, 256, 0, stream>>>(txtf, Wt1, bt1, H1t, N_ITEMS, 256, TXT_DIM, 1);
    }

    // ---- layer 2 + shared Wd:  fused = (0.5*(vis2+txt2)) @ Wd^T + bd ----
    linear64<<<(N_ITEMS + 3) / 4, 256, 0, stream>>>(H1v, wv2T, bv2, s, N_ITEMS, 512, 1.0f, 0);
    linear64<<<(N_ITEMS + 3) / 4, 256, 0, stream>>>(H1t, wt2T, bt2, s, N_ITEMS, 256, 1.0f, 1);
    linear64<<<(N_ITEMS + 3) / 4, 256, 0, stream>>>(s, wdT, bd, cur0 + (size_t)N_USERS * 64,
                                                    N_ITEMS, 64, 0.5f, 0);

    // ---- assemble ego, write out[:, 0:64] ----
    ego_fill<<<(N_NODES * EMB + 255) / 256, 256, 0, stream>>>(emb, cur0, out);

    // ---- propagation layer 1 (gather SpMM, no atomics) ----
    spmm_gather<<<(N_NODES + 3) / 4, 256, 0, stream>>>(row_ptr, col_s, val_s, cur0, nb);
    concat_lin<<<(N_NODES + 3) / 4, 256, 0, stream>>>(cur0, nb, wc0T, bc0, cur1, out, 64);

    // ---- propagation layer 2 ----
    spmm_gather<<<(N_NODES + 3) / 4, 256, 0, stream>>>(row_ptr, col_s, val_s, cur1, nb);
    concat_lin<<<(N_NODES + 3) / 4, 256, 0, stream>>>(cur1, nb, wc1T, bc1, nullptr, out, 128);
}

// Round 3
// 1659.309 us; speedup vs baseline: 1.1562x; 1.0251x over previous
//
#include <hip/hip_runtime.h>
#include <hip/hip_bf16.h>
#include <cstddef>

#define N_USERS 50000
#define N_ITEMS 10000
#define N_NODES 100000
#define EMB 64
#define NNZ_E 1600000
#define VIS_DIM 2048
#define TXT_DIM 300

typedef short bf16x8 __attribute__((ext_vector_type(8)));
typedef float f32x4  __attribute__((ext_vector_type(4)));

__device__ inline unsigned short f2bf(float x) {
    __hip_bfloat16 h = __float2bfloat16(x);
    return __builtin_bit_cast(unsigned short, h);
}
__device__ inline float bf2f(unsigned short u) {
    unsigned int t = ((unsigned int)u) << 16;
    float f;
    __builtin_memcpy(&f, &t, 4);
    return f;
}

// ---------------------------------------------------------------------------
// Split-precision bf16 MFMA GEMM: C[M,N] = act(A[M,K] @ W[N,K]^T + bias[N]).
// A ~= Ah+Al (bf16 each), W ~= Wh+Wl; C = Ah@Wh + Ah@Wl + Al@Wh (err ~2^-18).
// 64x64 tile, BK=64, 256 threads = 4 waves, each wave owns a 32x32 quadrant
// as 2x2 fragments of mfma_f32_16x16x32_bf16.
// LDS rows padded to 72 bf16 (144B): fragment reads are 2-way-max aliased.
// ---------------------------------------------------------------------------
#define LDW 72

__global__ __launch_bounds__(256) void gemm_mfma3(
    const float* __restrict__ A, const float* __restrict__ W,
    const float* __restrict__ bias, float* __restrict__ C,
    int M, int N, int K, int relu)
{
    __shared__ unsigned short Ah[64][LDW], Al[64][LDW];
    __shared__ unsigned short Wh[64][LDW], Wl[64][LDW];

    const int t  = threadIdx.x;
    const int w  = t >> 6;        // wave 0..3
    const int l  = t & 63;        // lane
    const int l16 = l & 15;
    const int lq  = l >> 4;       // quad 0..3
    const int m0 = blockIdx.y * 64;
    const int n0 = blockIdx.x * 64;
    const int mh = (w & 1) * 32;  // wave's m quadrant
    const int nh = (w >> 1) * 32; // wave's n quadrant

    const int sr = t >> 4;        // 0..15: staging row within 16-row pass
    const int sk = (t & 15) * 4;  // staging k offset 0..60

    f32x4 acc[2][2] = {};

    for (int k0 = 0; k0 < K; k0 += 64) {
        // ---- stage A and W: fp32 -> (hi, lo) bf16 in LDS ----
        #pragma unroll
        for (int p = 0; p < 4; p++) {
            int r = p * 16 + sr;
            // A
            {
                float v[4] = {0.f, 0.f, 0.f, 0.f};
                int m = m0 + r;
                if (m < M) {
                    const float* g = A + (size_t)m * K + k0 + sk;
                    if (k0 + sk + 3 < K) {
                        float4 q = *(const float4*)g;
                        v[0] = q.x; v[1] = q.y; v[2] = q.z; v[3] = q.w;
                    } else {
                        #pragma unroll
                        for (int i = 0; i < 4; i++)
                            if (k0 + sk + i < K) v[i] = g[i];
                    }
                }
                ushort4 hi, lo;
                hi.x = f2bf(v[0]); lo.x = f2bf(v[0] - bf2f(hi.x));
                hi.y = f2bf(v[1]); lo.y = f2bf(v[1] - bf2f(hi.y));
                hi.z = f2bf(v[2]); lo.z = f2bf(v[2] - bf2f(hi.z));
                hi.w = f2bf(v[3]); lo.w = f2bf(v[3] - bf2f(hi.w));
                *(ushort4*)&Ah[r][sk] = hi;
                *(ushort4*)&Al[r][sk] = lo;
            }
            // W
            {
                float v[4] = {0.f, 0.f, 0.f, 0.f};
                int n = n0 + r;
                if (n < N) {
                    const float* g = W + (size_t)n * K + k0 + sk;
                    if (k0 + sk + 3 < K) {
                        float4 q = *(const float4*)g;
                        v[0] = q.x; v[1] = q.y; v[2] = q.z; v[3] = q.w;
                    } else {
                        #pragma unroll
                        for (int i = 0; i < 4; i++)
                            if (k0 + sk + i < K) v[i] = g[i];
                    }
                }
                ushort4 hi, lo;
                hi.x = f2bf(v[0]); lo.x = f2bf(v[0] - bf2f(hi.x));
                hi.y = f2bf(v[1]); lo.y = f2bf(v[1] - bf2f(hi.y));
                hi.z = f2bf(v[2]); lo.z = f2bf(v[2] - bf2f(hi.z));
                hi.w = f2bf(v[3]); lo.w = f2bf(v[3] - bf2f(hi.w));
                *(ushort4*)&Wh[r][sk] = hi;
                *(ushort4*)&Wl[r][sk] = lo;
            }
        }
        __syncthreads();

        // ---- MFMA over two k-chunks of 32 ----
        #pragma unroll
        for (int c = 0; c < 64; c += 32) {
            int kq = c + lq * 8;
            bf16x8 ah[2], al[2], bh[2], bl[2];
            #pragma unroll
            for (int mi = 0; mi < 2; mi++) {
                ah[mi] = *(const bf16x8*)&Ah[mh + mi * 16 + l16][kq];
                al[mi] = *(const bf16x8*)&Al[mh + mi * 16 + l16][kq];
            }
            #pragma unroll
            for (int ni = 0; ni < 2; ni++) {
                bh[ni] = *(const bf16x8*)&Wh[nh + ni * 16 + l16][kq];
                bl[ni] = *(const bf16x8*)&Wl[nh + ni * 16 + l16][kq];
            }
            #pragma unroll
            for (int mi = 0; mi < 2; mi++)
                #pragma unroll
                for (int ni = 0; ni < 2; ni++) {
                    acc[mi][ni] = __builtin_amdgcn_mfma_f32_16x16x32_bf16(
                        ah[mi], bh[ni], acc[mi][ni], 0, 0, 0);
                    acc[mi][ni] = __builtin_amdgcn_mfma_f32_16x16x32_bf16(
                        ah[mi], bl[ni], acc[mi][ni], 0, 0, 0);
                    acc[mi][ni] = __builtin_amdgcn_mfma_f32_16x16x32_bf16(
                        al[mi], bh[ni], acc[mi][ni], 0, 0, 0);
                }
        }
        __syncthreads();
    }

    // ---- epilogue: D[row=(lq*4+r), col=l16] per 16x16 fragment ----
    #pragma unroll
    for (int ni = 0; ni < 2; ni++) {
        int col = n0 + nh + ni * 16 + l16;
        float bcol = bias[col];
        #pragma unroll
        for (int mi = 0; mi < 2; mi++) {
            #pragma unroll
            for (int r = 0; r < 4; r++) {
                int row = m0 + mh + mi * 16 + lq * 4 + r;
                if (row >= M) continue;
                float v = acc[mi][ni][r] + bcol;
                if (relu) v = fmaxf(v, 0.f);
                C[(size_t)row * N + col] = v;
            }
        }
    }
}

// ---------------------------------------------------------------------------
__global__ void transp64(const float* __restrict__ W, float* __restrict__ wT, int K)
{
    int i = blockIdx.x * 256 + threadIdx.x;
    if (i >= 64 * K) return;
    int d = i / K, k = i - d * K;
    wT[k * 64 + d] = W[i];
}

// ---------------------------------------------------------------------------
__global__ __launch_bounds__(256) void linear64(
    const float* __restrict__ in, const float* __restrict__ wT,
    const float* __restrict__ bias, float* __restrict__ out,
    int M, int K, float in_scale, int add)
{
    int t = threadIdx.x;
    int d = t & 63;
    int m = blockIdx.x * 4 + (t >> 6);
    if (m >= M) return;
    const float* x = in + (size_t)m * K;
    float acc = 0.f;
    for (int k = 0; k < K; k++) acc += x[k] * wT[k * 64 + d];
    float r = acc * in_scale + bias[d];
    if (add) out[(size_t)m * 64 + d] += r;
    else     out[(size_t)m * 64 + d]  = r;
}

// ---------------------------------------------------------------------------
__global__ void ego_fill(const float* __restrict__ emb, float* __restrict__ cur0,
                         float* __restrict__ out_full)
{
    int tid = blockIdx.x * 256 + threadIdx.x;
    if (tid >= N_NODES * EMB) return;
    int m = tid >> 6, d = tid & 63;
    float v;
    if (m < N_USERS || m >= N_USERS + N_ITEMS) {
        v = emb[tid];
        cur0[tid] = v;
    } else {
        v = cur0[tid];
    }
    out_full[(size_t)m * 192 + d] = v;
}

// ---------------------------------------------------------------------------
// CSR build: histogram -> exclusive scan -> scatter
// ---------------------------------------------------------------------------
__global__ __launch_bounds__(256) void hist_rows(
    const int* __restrict__ row, int* __restrict__ cnt, int nnz)
{
    int e = blockIdx.x * 256 + threadIdx.x;
    if (e >= nnz) return;
    atomicAdd(&cnt[row[e]], 1);
}

__global__ __launch_bounds__(256) void scan1(int* __restrict__ cnt,
                                             int* __restrict__ bsum, int n)
{
    __shared__ int part[256];
    int t = threadIdx.x;
    int base = blockIdx.x * 1024 + t * 4;
    int v0 = 0, v1 = 0, v2 = 0, v3 = 0;
    if (base + 0 < n) v0 = cnt[base + 0];
    if (base + 1 < n) v1 = cnt[base + 1];
    if (base + 2 < n) v2 = cnt[base + 2];
    if (base + 3 < n) v3 = cnt[base + 3];
    int s = v0 + v1 + v2 + v3;
    part[t] = s;
    __syncthreads();
    for (int off = 1; off < 256; off <<= 1) {
        int x = (t >= off) ? part[t - off] : 0;
        __syncthreads();
        part[t] += x;
        __syncthreads();
    }
    int excl = part[t] - s;
    if (t == 255) bsum[blockIdx.x] = part[t];
    if (base + 0 < n) cnt[base + 0] = excl;
    if (base + 1 < n) cnt[base + 1] = excl + v0;
    if (base + 2 < n) cnt[base + 2] = excl + v0 + v1;
    if (base + 3 < n) cnt[base + 3] = excl + v0 + v1 + v2;
}

__global__ void scan2(int* __restrict__ bsum, int nb)
{
    if (threadIdx.x == 0 && blockIdx.x == 0) {
        int acc = 0;
        for (int i = 0; i < nb; i++) { int v = bsum[i]; bsum[i] = acc; acc += v; }
    }
}

__global__ __launch_bounds__(256) void scan3(
    const int* __restrict__ excl, const int* __restrict__ bsum,
    int* __restrict__ row_ptr, int* __restrict__ row_cur, int n, int nnz)
{
    int i = blockIdx.x * 256 + threadIdx.x;
    if (i > n) return;
    if (i == n) { row_ptr[n] = nnz; return; }
    int v = excl[i] + bsum[i >> 10];
    row_ptr[i] = v;
    row_cur[i] = v;
}

__global__ __launch_bounds__(256) void scatter_csr(
    const int* __restrict__ row, const int* __restrict__ col,
    const float* __restrict__ val, int* __restrict__ row_cur,
    int* __restrict__ col_s, float* __restrict__ val_s, int nnz)
{
    int e = blockIdx.x * 256 + threadIdx.x;
    if (e >= nnz) return;
    int r = row[e];
    int p = atomicAdd(&row_cur[r], 1);
    col_s[p] = col[e];
    val_s[p] = val[e];
}

// ---------------------------------------------------------------------------
// Gather SpMM: one wave per row, no atomics.
// ---------------------------------------------------------------------------
__global__ __launch_bounds__(256) void spmm_gather(
    const int* __restrict__ row_ptr, const int* __restrict__ col_s,
    const float* __restrict__ val_s, const float* __restrict__ cur,
    float* __restrict__ nb)
{
    int t = threadIdx.x;
    int d = t & 63;
    int m = blockIdx.x * 4 + (t >> 6);
    if (m >= N_NODES) return;
    int beg = row_ptr[m], end = row_ptr[m + 1];
    float acc = 0.f;
    for (int j = beg; j < end; j++) {
        int   c = col_s[j];
        float v = val_s[j];
        acc += v * cur[(size_t)c * 64 + d];
    }
    nb[(size_t)m * 64 + d] = acc;
}

// ---------------------------------------------------------------------------
__global__ __launch_bounds__(256) void concat_lin(
    const float* __restrict__ cur, const float* __restrict__ nb,
    const float* __restrict__ wT, const float* __restrict__ bias,
    float* __restrict__ out_cur, float* __restrict__ out_full, int col_off)
{
    int t = threadIdx.x;
    int d = t & 63;
    int m = blockIdx.x * 4 + (t >> 6);
    if (m >= N_NODES) return;
    const float* x1 = cur + (size_t)m * 64;
    const float* x2 = nb  + (size_t)m * 64;
    float acc = bias[d];
    #pragma unroll 4
    for (int k = 0; k < 64; k++) acc += x1[k] * wT[k * 64 + d];
    #pragma unroll 4
    for (int k = 0; k < 64; k++) acc += x2[k] * wT[(64 + k) * 64 + d];
    float r = (acc > 0.f) ? acc : 0.01f * acc;
    if (out_cur) out_cur[(size_t)m * 64 + d] = r;
    out_full[(size_t)m * 192 + col_off + d] = r;
}

// ---------------------------------------------------------------------------
extern "C" void kernel_launch(void* const* d_in, const int* in_sizes, int n_in,
                              void* d_out, int out_size, void* d_ws, size_t ws_size,
                              hipStream_t stream)
{
    const int*   adj_row = (const int*)  d_in[0];
    const int*   adj_col = (const int*)  d_in[1];
    const float* adj_val = (const float*)d_in[2];
    const float* emb     = (const float*)d_in[3];
    const float* visf    = (const float*)d_in[4];
    const float* txtf    = (const float*)d_in[5];
    const float* Wv1 = (const float*)d_in[6];  const float* bv1 = (const float*)d_in[7];
    const float* Wv2 = (const float*)d_in[8];  const float* bv2 = (const float*)d_in[9];
    const float* Wt1 = (const float*)d_in[10]; const float* bt1 = (const float*)d_in[11];
    const float* Wt2 = (const float*)d_in[12]; const float* bt2 = (const float*)d_in[13];
    const float* Wd  = (const float*)d_in[14]; const float* bd  = (const float*)d_in[15];
    const float* Wc0 = (const float*)d_in[16]; const float* bc0 = (const float*)d_in[17];
    const float* Wc1 = (const float*)d_in[18]; const float* bc1 = (const float*)d_in[19];

    float* out = (float*)d_out;
    float* ws  = (float*)d_ws;

    // workspace layout (float offsets)
    float* H1v  = ws + 0;          // 10000*512          [dead after linear64 #1]
    float* H1t  = ws + 5120000;    // 10000*256          [dead after linear64 #2]
    float* nb   = ws + 0;          // 100000*64 (reuses H1v/H1t region)
    float* s    = ws + 7680000;    // 10000*64
    float* cur0 = ws + 8320000;    // 100000*64
    float* cur1 = ws + 14720000;   // 100000*64
    float* wv2T = ws + 21120000;   // 512*64
    float* wt2T = wv2T + 32768;    // 256*64
    float* wdT  = wt2T + 16384;    // 64*64
    float* wc0T = wdT  + 4096;     // 128*64
    float* wc1T = wc0T + 8192;     // 128*64
    // CSR scratch
    int*   col_s   = (int*)  (ws + 21200000);  // 1.6M
    float* val_s   =          ws + 22800000;   // 1.6M
    int*   row_ptr = (int*)  (ws + 24400000);  // 100001
    int*   row_cur = (int*)  (ws + 24510000);  // 100000
    int*   cnt     = (int*)  (ws + 24620000);  // 100000 (scanned in place)
    int*   bsum    = (int*)  (ws + 24730000);  // 98

    const int NBLK = (N_NODES + 1023) / 1024;  // 98

    // ---- weight transposes (tiny) ----
    transp64<<<(64 * 512 + 255) / 256, 256, 0, stream>>>(Wv2, wv2T, 512);
    transp64<<<(64 * 256 + 255) / 256, 256, 0, stream>>>(Wt2, wt2T, 256);
    transp64<<<(64 * 64  + 255) / 256, 256, 0, stream>>>(Wd,  wdT,  64);
    transp64<<<(64 * 128 + 255) / 256, 256, 0, stream>>>(Wc0, wc0T, 128);
    transp64<<<(64 * 128 + 255) / 256, 256, 0, stream>>>(Wc1, wc1T, 128);

    // ---- CSR build (reused for both propagation layers) ----
    hipMemsetAsync(cnt, 0, N_NODES * sizeof(int), stream);
    hist_rows<<<(NNZ_E + 255) / 256, 256, 0, stream>>>(adj_row, cnt, NNZ_E);
    scan1<<<NBLK, 256, 0, stream>>>(cnt, bsum, N_NODES);
    scan2<<<1, 64, 0, stream>>>(bsum, NBLK);
    scan3<<<(N_NODES + 256) / 256, 256, 0, stream>>>(cnt, bsum, row_ptr, row_cur,
                                                     N_NODES, NNZ_E);
    scatter_csr<<<(NNZ_E + 255) / 256, 256, 0, stream>>>(adj_row, adj_col, adj_val,
                                                         row_cur, col_s, val_s, NNZ_E);

    // ---- item MLP layer 1: split-bf16 MFMA GEMMs ----
    {
        dim3 g(512 / 64, (N_ITEMS + 63) / 64);
        gemm_mfma3<<<g, 256, 0, stream>>>(visf, Wv1, bv1, H1v, N_ITEMS, 512, VIS_DIM, 1);
    }
    {
        dim3 g(256 / 64, (N_ITEMS + 63) / 64);
        gemm_mfma3<<<g, 256, 0, stream>>>(txtf, Wt1, bt1, H1t, N_ITEMS, 256, TXT_DIM, 1);
    }

    // ---- layer 2 + shared Wd:  fused = (0.5*(vis2+txt2)) @ Wd^T + bd ----
    linear64<<<(N_ITEMS + 3) / 4, 256, 0, stream>>>(H1v, wv2T, bv2, s, N_ITEMS, 512, 1.0f, 0);
    linear64<<<(N_ITEMS + 3) / 4, 256, 0, stream>>>(H1t, wt2T, bt2, s, N_ITEMS, 256, 1.0f, 1);
    linear64<<<(N_ITEMS + 3) / 4, 256, 0, stream>>>(s, wdT, bd, cur0 + (size_t)N_USERS * 64,
                                                    N_ITEMS, 64, 0.5f, 0);

    // ---- assemble ego, write out[:, 0:64] ----
    ego_fill<<<(N_NODES * EMB + 255) / 256, 256, 0, stream>>>(emb, cur0, out);

    // ---- propagation layer 1 (gather SpMM, no atomics) ----
    spmm_gather<<<(N_NODES + 3) / 4, 256, 0, stream>>>(row_ptr, col_s, val_s, cur0, nb);
    concat_lin<<<(N_NODES + 3) / 4, 256, 0, stream>>>(cur0, nb, wc0T, bc0, cur1, out, 64);

    // ---- propagation layer 2 ----
    spmm_gather<<<(N_NODES + 3) / 4, 256, 0, stream>>>(row_ptr, col_s, val_s, cur1, nb);
    concat_lin<<<(N_NODES + 3) / 4, 256, 0, stream>>>(cur1, nb, wc1T, bc1, nullptr, out, 128);
}

// Round 4
// 1321.974 us; speedup vs baseline: 1.4512x; 1.2552x over previous
//
#include <hip/hip_runtime.h>
#include <hip/hip_bf16.h>
#include <cstddef>

#define N_USERS 50000
#define N_ITEMS 10000
#define N_NODES 100000
#define EMB 64
#define NNZ_E 1600000
#define VIS_DIM 2048
#define TXT_DIM 300

typedef short bf16x8 __attribute__((ext_vector_type(8)));
typedef float f32x4  __attribute__((ext_vector_type(4)));

__device__ inline unsigned short f2bf(float x) {
    __hip_bfloat16 h = __float2bfloat16(x);
    return __builtin_bit_cast(unsigned short, h);
}
__device__ inline float bf2f(unsigned short u) {
    unsigned int t = ((unsigned int)u) << 16;
    float f;
    __builtin_memcpy(&f, &t, 4);
    return f;
}

// ---------------------------------------------------------------------------
// Split-precision bf16 MFMA GEMM v2: C[M,N] = act(A[M,K] @ W[N,K]^T + bias).
// TM=128, TN=128, BK=32. 256 threads = 4 waves in 2x2, each wave 64x64 as
// 4x4 frags of mfma_f32_16x16x32_bf16, 3-term split (Ah*Wh + Ah*Wl + Al*Wh).
// Register-prefetch pipeline: global loads for k0+1 issued before the MFMA
// block so memory latency overlaps compute.
// LDS rows padded 32->40 shorts (80 B).
// ---------------------------------------------------------------------------
#define GLDW 40

__global__ __launch_bounds__(256, 2) void gemm_bf3(
    const float* __restrict__ A, const float* __restrict__ W,
    const float* __restrict__ bias, float* __restrict__ C,
    int M, int N, int K, int relu)
{
    __shared__ unsigned short Ah[128][GLDW], Al[128][GLDW];
    __shared__ unsigned short Wh[128][GLDW], Wl[128][GLDW];

    const int t   = threadIdx.x;
    const int w   = t >> 6;
    const int l   = t & 63;
    const int l16 = l & 15;
    const int lq  = l >> 4;
    const int m0  = blockIdx.y * 128;
    const int n0  = blockIdx.x * 128;
    const int mh  = (w & 1) * 64;
    const int nh  = (w >> 1) * 64;

    // staging chunk map: chunk c (0..511) per matrix: row = c>>2, kc = c&3
    // thread t owns chunks {t, t+256}; 8 consecutive k-elements per chunk.
    const int r0 = t >> 2,          kc0 = t & 3;
    const int r1 = (t + 256) >> 2,  kc1 = t & 3;   // (t+256)&3 == t&3

    f32x4 acc[4][4] = {};

    const int kiters = (K + 31) / 32;

    float pa[2][8], pw[2][8];

    // ---- prologue: load tile 0 into regs ----
    {
        const int k0 = 0;
        #pragma unroll
        for (int p = 0; p < 2; p++) {
            int row = p ? r1 : r0, kc = p ? kc1 : kc0;
            int rg = m0 + row; if (rg >= M) rg = M - 1;
            const float* g = A + (size_t)rg * K + k0 + kc * 8;
            if (k0 + kc * 8 + 7 < K) {
                float4 q0 = *(const float4*)g, q1 = *(const float4*)(g + 4);
                pa[p][0]=q0.x; pa[p][1]=q0.y; pa[p][2]=q0.z; pa[p][3]=q0.w;
                pa[p][4]=q1.x; pa[p][5]=q1.y; pa[p][6]=q1.z; pa[p][7]=q1.w;
            } else {
                #pragma unroll
                for (int i = 0; i < 8; i++)
                    pa[p][i] = (k0 + kc * 8 + i < K) ? g[i] : 0.f;
            }
            int ng = n0 + row; if (ng >= N) ng = N - 1;
            const float* gw = W + (size_t)ng * K + k0 + kc * 8;
            if (k0 + kc * 8 + 7 < K) {
                float4 q0 = *(const float4*)gw, q1 = *(const float4*)(gw + 4);
                pw[p][0]=q0.x; pw[p][1]=q0.y; pw[p][2]=q0.z; pw[p][3]=q0.w;
                pw[p][4]=q1.x; pw[p][5]=q1.y; pw[p][6]=q1.z; pw[p][7]=q1.w;
            } else {
                #pragma unroll
                for (int i = 0; i < 8; i++)
                    pw[p][i] = (k0 + kc * 8 + i < K) ? gw[i] : 0.f;
            }
        }
    }

    for (int kt = 0; kt < kiters; kt++) {
        // ---- convert prefetched regs -> LDS hi/lo ----
        #pragma unroll
        for (int p = 0; p < 2; p++) {
            int row = p ? r1 : r0, kc = p ? kc1 : kc0;
            bf16x8 hi, lo;
            #pragma unroll
            for (int i = 0; i < 8; i++) {
                unsigned short h = f2bf(pa[p][i]);
                hi[i] = (short)h;
                lo[i] = (short)f2bf(pa[p][i] - bf2f(h));
            }
            *(bf16x8*)&Ah[row][kc * 8] = hi;
            *(bf16x8*)&Al[row][kc * 8] = lo;
            #pragma unroll
            for (int i = 0; i < 8; i++) {
                unsigned short h = f2bf(pw[p][i]);
                hi[i] = (short)h;
                lo[i] = (short)f2bf(pw[p][i] - bf2f(h));
            }
            *(bf16x8*)&Wh[row][kc * 8] = hi;
            *(bf16x8*)&Wl[row][kc * 8] = lo;
        }
        __syncthreads();

        // ---- issue next tile's global loads (overlap with MFMA below) ----
        if (kt + 1 < kiters) {
            const int k0 = (kt + 1) * 32;
            #pragma unroll
            for (int p = 0; p < 2; p++) {
                int row = p ? r1 : r0, kc = p ? kc1 : kc0;
                int rg = m0 + row; if (rg >= M) rg = M - 1;
                const float* g = A + (size_t)rg * K + k0 + kc * 8;
                if (k0 + kc * 8 + 7 < K) {
                    float4 q0 = *(const float4*)g, q1 = *(const float4*)(g + 4);
                    pa[p][0]=q0.x; pa[p][1]=q0.y; pa[p][2]=q0.z; pa[p][3]=q0.w;
                    pa[p][4]=q1.x; pa[p][5]=q1.y; pa[p][6]=q1.z; pa[p][7]=q1.w;
                } else {
                    #pragma unroll
                    for (int i = 0; i < 8; i++)
                        pa[p][i] = (k0 + kc * 8 + i < K) ? g[i] : 0.f;
                }
                int ng = n0 + row; if (ng >= N) ng = N - 1;
                const float* gw = W + (size_t)ng * K + k0 + kc * 8;
                if (k0 + kc * 8 + 7 < K) {
                    float4 q0 = *(const float4*)gw, q1 = *(const float4*)(gw + 4);
                    pw[p][0]=q0.x; pw[p][1]=q0.y; pw[p][2]=q0.z; pw[p][3]=q0.w;
                    pw[p][4]=q1.x; pw[p][5]=q1.y; pw[p][6]=q1.z; pw[p][7]=q1.w;
                } else {
                    #pragma unroll
                    for (int i = 0; i < 8; i++)
                        pw[p][i] = (k0 + kc * 8 + i < K) ? gw[i] : 0.f;
                }
            }
        }

        // ---- MFMA: 4x4 frags x 3 split terms ----
        {
            bf16x8 ah[4], al[4];
            #pragma unroll
            for (int mi = 0; mi < 4; mi++) {
                ah[mi] = *(const bf16x8*)&Ah[mh + mi * 16 + l16][lq * 8];
                al[mi] = *(const bf16x8*)&Al[mh + mi * 16 + l16][lq * 8];
            }
            #pragma unroll
            for (int ni = 0; ni < 4; ni++) {
                bf16x8 bh = *(const bf16x8*)&Wh[nh + ni * 16 + l16][lq * 8];
                bf16x8 bl = *(const bf16x8*)&Wl[nh + ni * 16 + l16][lq * 8];
                #pragma unroll
                for (int mi = 0; mi < 4; mi++) {
                    acc[mi][ni] = __builtin_amdgcn_mfma_f32_16x16x32_bf16(
                        ah[mi], bh, acc[mi][ni], 0, 0, 0);
                    acc[mi][ni] = __builtin_amdgcn_mfma_f32_16x16x32_bf16(
                        ah[mi], bl, acc[mi][ni], 0, 0, 0);
                    acc[mi][ni] = __builtin_amdgcn_mfma_f32_16x16x32_bf16(
                        al[mi], bh, acc[mi][ni], 0, 0, 0);
                }
            }
        }
        __syncthreads();
    }

    // ---- epilogue ----
    #pragma unroll
    for (int ni = 0; ni < 4; ni++) {
        int col = n0 + nh + ni * 16 + l16;
        float bcol = bias[col];
        #pragma unroll
        for (int mi = 0; mi < 4; mi++) {
            #pragma unroll
            for (int r = 0; r < 4; r++) {
                int row = m0 + mh + mi * 16 + lq * 4 + r;
                if (row >= M) continue;
                float v = acc[mi][ni][r] + bcol;
                if (relu) v = fmaxf(v, 0.f);
                C[(size_t)row * N + col] = v;
            }
        }
    }
}

// ---------------------------------------------------------------------------
__global__ void transp64(const float* __restrict__ W, float* __restrict__ wT, int K)
{
    int i = blockIdx.x * 256 + threadIdx.x;
    if (i >= 64 * K) return;
    int d = i / K, k = i - d * K;
    wT[k * 64 + d] = W[i];
}

// ---------------------------------------------------------------------------
__global__ __launch_bounds__(256) void linear64(
    const float* __restrict__ in, const float* __restrict__ wT,
    const float* __restrict__ bias, float* __restrict__ out,
    int M, int K, float in_scale, int add)
{
    int t = threadIdx.x;
    int d = t & 63;
    int m = blockIdx.x * 4 + (t >> 6);
    if (m >= M) return;
    const float* x = in + (size_t)m * K;
    float acc = 0.f;
    for (int k = 0; k < K; k++) acc += x[k] * wT[k * 64 + d];
    float r = acc * in_scale + bias[d];
    if (add) out[(size_t)m * 64 + d] += r;
    else     out[(size_t)m * 64 + d]  = r;
}

// ---------------------------------------------------------------------------
__global__ void ego_fill(const float* __restrict__ emb, float* __restrict__ cur0,
                         float* __restrict__ out_full)
{
    int tid = blockIdx.x * 256 + threadIdx.x;
    if (tid >= N_NODES * EMB) return;
    int m = tid >> 6, d = tid & 63;
    float v;
    if (m < N_USERS || m >= N_USERS + N_ITEMS) {
        v = emb[tid];
        cur0[tid] = v;
    } else {
        v = cur0[tid];
    }
    out_full[(size_t)m * 192 + d] = v;
}

// ---------------------------------------------------------------------------
// CSR build: histogram -> exclusive scan -> scatter
// ---------------------------------------------------------------------------
__global__ __launch_bounds__(256) void hist_rows(
    const int* __restrict__ row, int* __restrict__ cnt, int nnz)
{
    int e = blockIdx.x * 256 + threadIdx.x;
    if (e >= nnz) return;
    atomicAdd(&cnt[row[e]], 1);
}

__global__ __launch_bounds__(256) void scan1(int* __restrict__ cnt,
                                             int* __restrict__ bsum, int n)
{
    __shared__ int part[256];
    int t = threadIdx.x;
    int base = blockIdx.x * 1024 + t * 4;
    int v0 = 0, v1 = 0, v2 = 0, v3 = 0;
    if (base + 0 < n) v0 = cnt[base + 0];
    if (base + 1 < n) v1 = cnt[base + 1];
    if (base + 2 < n) v2 = cnt[base + 2];
    if (base + 3 < n) v3 = cnt[base + 3];
    int s = v0 + v1 + v2 + v3;
    part[t] = s;
    __syncthreads();
    for (int off = 1; off < 256; off <<= 1) {
        int x = (t >= off) ? part[t - off] : 0;
        __syncthreads();
        part[t] += x;
        __syncthreads();
    }
    int excl = part[t] - s;
    if (t == 255) bsum[blockIdx.x] = part[t];
    if (base + 0 < n) cnt[base + 0] = excl;
    if (base + 1 < n) cnt[base + 1] = excl + v0;
    if (base + 2 < n) cnt[base + 2] = excl + v0 + v1;
    if (base + 3 < n) cnt[base + 3] = excl + v0 + v1 + v2;
}

__global__ void scan2(int* __restrict__ bsum, int nb)
{
    if (threadIdx.x == 0 && blockIdx.x == 0) {
        int acc = 0;
        for (int i = 0; i < nb; i++) { int v = bsum[i]; bsum[i] = acc; acc += v; }
    }
}

__global__ __launch_bounds__(256) void scan3(
    const int* __restrict__ excl, const int* __restrict__ bsum,
    int* __restrict__ row_ptr, int* __restrict__ row_cur, int n, int nnz)
{
    int i = blockIdx.x * 256 + threadIdx.x;
    if (i > n) return;
    if (i == n) { row_ptr[n] = nnz; return; }
    int v = excl[i] + bsum[i >> 10];
    row_ptr[i] = v;
    row_cur[i] = v;
}

__global__ __launch_bounds__(256) void scatter_csr(
    const int* __restrict__ row, const int* __restrict__ col,
    const float* __restrict__ val, int* __restrict__ row_cur,
    int* __restrict__ col_s, float* __restrict__ val_s, int nnz)
{
    int e = blockIdx.x * 256 + threadIdx.x;
    if (e >= nnz) return;
    int r = row[e];
    int p = atomicAdd(&row_cur[r], 1);
    col_s[p] = col[e];
    val_s[p] = val[e];
}

// ---------------------------------------------------------------------------
// Gather SpMM v2: one wave per row; 64 lanes = 4 edge-slots x 16 dim-groups.
// float4 gathers, 4 edges in flight, shuffle-xor reduce across edge slots.
// ---------------------------------------------------------------------------
__global__ __launch_bounds__(256) void spmm_gather(
    const int* __restrict__ row_ptr, const int* __restrict__ col_s,
    const float* __restrict__ val_s, const float* __restrict__ cur,
    float* __restrict__ nb)
{
    int t  = threadIdx.x;
    int wv = t >> 6;
    int l  = t & 63;
    int eg = l >> 4;          // edge slot 0..3
    int dg = l & 15;          // dim group (4 floats)
    int m = blockIdx.x * 4 + wv;
    if (m >= N_NODES) return;
    int beg = row_ptr[m], end = row_ptr[m + 1];
    float ax = 0.f, ay = 0.f, az = 0.f, aw = 0.f;
    for (int j = beg + eg; j < end; j += 4) {
        int   c = col_s[j];
        float v = val_s[j];
        float4 cv = *(const float4*)&cur[(size_t)c * 64 + dg * 4];
        ax += v * cv.x; ay += v * cv.y; az += v * cv.z; aw += v * cv.w;
    }
    ax += __shfl_xor(ax, 16, 64); ay += __shfl_xor(ay, 16, 64);
    az += __shfl_xor(az, 16, 64); aw += __shfl_xor(aw, 16, 64);
    ax += __shfl_xor(ax, 32, 64); ay += __shfl_xor(ay, 32, 64);
    az += __shfl_xor(az, 32, 64); aw += __shfl_xor(aw, 32, 64);
    if (eg == 0) {
        float4 r; r.x = ax; r.y = ay; r.z = az; r.w = aw;
        *(float4*)&nb[(size_t)m * 64 + dg * 4] = r;
    }
}

// ---------------------------------------------------------------------------
__global__ __launch_bounds__(256) void concat_lin(
    const float* __restrict__ cur, const float* __restrict__ nb,
    const float* __restrict__ wT, const float* __restrict__ bias,
    float* __restrict__ out_cur, float* __restrict__ out_full, int col_off)
{
    int t = threadIdx.x;
    int d = t & 63;
    int m = blockIdx.x * 4 + (t >> 6);
    if (m >= N_NODES) return;
    const float* x1 = cur + (size_t)m * 64;
    const float* x2 = nb  + (size_t)m * 64;
    float acc = bias[d];
    #pragma unroll 4
    for (int k = 0; k < 64; k++) acc += x1[k] * wT[k * 64 + d];
    #pragma unroll 4
    for (int k = 0; k < 64; k++) acc += x2[k] * wT[(64 + k) * 64 + d];
    float r = (acc > 0.f) ? acc : 0.01f * acc;
    if (out_cur) out_cur[(size_t)m * 64 + d] = r;
    out_full[(size_t)m * 192 + col_off + d] = r;
}

// ---------------------------------------------------------------------------
extern "C" void kernel_launch(void* const* d_in, const int* in_sizes, int n_in,
                              void* d_out, int out_size, void* d_ws, size_t ws_size,
                              hipStream_t stream)
{
    const int*   adj_row = (const int*)  d_in[0];
    const int*   adj_col = (const int*)  d_in[1];
    const float* adj_val = (const float*)d_in[2];
    const float* emb     = (const float*)d_in[3];
    const float* visf    = (const float*)d_in[4];
    const float* txtf    = (const float*)d_in[5];
    const float* Wv1 = (const float*)d_in[6];  const float* bv1 = (const float*)d_in[7];
    const float* Wv2 = (const float*)d_in[8];  const float* bv2 = (const float*)d_in[9];
    const float* Wt1 = (const float*)d_in[10]; const float* bt1 = (const float*)d_in[11];
    const float* Wt2 = (const float*)d_in[12]; const float* bt2 = (const float*)d_in[13];
    const float* Wd  = (const float*)d_in[14]; const float* bd  = (const float*)d_in[15];
    const float* Wc0 = (const float*)d_in[16]; const float* bc0 = (const float*)d_in[17];
    const float* Wc1 = (const float*)d_in[18]; const float* bc1 = (const float*)d_in[19];

    float* out = (float*)d_out;
    float* ws  = (float*)d_ws;

    // workspace layout (float offsets) — unchanged from R2 (proven size)
    float* H1v  = ws + 0;          // 10000*512
    float* H1t  = ws + 5120000;    // 10000*256
    float* nb   = ws + 0;          // 100000*64 (reuses H1v/H1t region)
    float* s    = ws + 7680000;    // 10000*64
    float* cur0 = ws + 8320000;    // 100000*64
    float* cur1 = ws + 14720000;   // 100000*64
    float* wv2T = ws + 21120000;   // 512*64
    float* wt2T = wv2T + 32768;    // 256*64
    float* wdT  = wt2T + 16384;    // 64*64
    float* wc0T = wdT  + 4096;     // 128*64
    float* wc1T = wc0T + 8192;     // 128*64
    int*   col_s   = (int*)  (ws + 21200000);  // 1.6M
    float* val_s   =          ws + 22800000;   // 1.6M
    int*   row_ptr = (int*)  (ws + 24400000);  // 100001
    int*   row_cur = (int*)  (ws + 24510000);  // 100000
    int*   cnt     = (int*)  (ws + 24620000);  // 100000
    int*   bsum    = (int*)  (ws + 24730000);  // 98

    const int NBLK = (N_NODES + 1023) / 1024;  // 98

    // ---- weight transposes (tiny) ----
    transp64<<<(64 * 512 + 255) / 256, 256, 0, stream>>>(Wv2, wv2T, 512);
    transp64<<<(64 * 256 + 255) / 256, 256, 0, stream>>>(Wt2, wt2T, 256);
    transp64<<<(64 * 64  + 255) / 256, 256, 0, stream>>>(Wd,  wdT,  64);
    transp64<<<(64 * 128 + 255) / 256, 256, 0, stream>>>(Wc0, wc0T, 128);
    transp64<<<(64 * 128 + 255) / 256, 256, 0, stream>>>(Wc1, wc1T, 128);

    // ---- CSR build (reused for both propagation layers) ----
    hipMemsetAsync(cnt, 0, N_NODES * sizeof(int), stream);
    hist_rows<<<(NNZ_E + 255) / 256, 256, 0, stream>>>(adj_row, cnt, NNZ_E);
    scan1<<<NBLK, 256, 0, stream>>>(cnt, bsum, N_NODES);
    scan2<<<1, 64, 0, stream>>>(bsum, NBLK);
    scan3<<<(N_NODES + 256) / 256, 256, 0, stream>>>(cnt, bsum, row_ptr, row_cur,
                                                     N_NODES, NNZ_E);
    scatter_csr<<<(NNZ_E + 255) / 256, 256, 0, stream>>>(adj_row, adj_col, adj_val,
                                                         row_cur, col_s, val_s, NNZ_E);

    // ---- item MLP layer 1: pipelined split-bf16 MFMA GEMMs ----
    {
        dim3 g(512 / 128, (N_ITEMS + 127) / 128);
        gemm_bf3<<<g, 256, 0, stream>>>(visf, Wv1, bv1, H1v, N_ITEMS, 512, VIS_DIM, 1);
    }
    {
        dim3 g(256 / 128, (N_ITEMS + 127) / 128);
        gemm_bf3<<<g, 256, 0, stream>>>(txtf, Wt1, bt1, H1t, N_ITEMS, 256, TXT_DIM, 1);
    }

    // ---- layer 2 + shared Wd:  fused = (0.5*(vis2+txt2)) @ Wd^T + bd ----
    linear64<<<(N_ITEMS + 3) / 4, 256, 0, stream>>>(H1v, wv2T, bv2, s, N_ITEMS, 512, 1.0f, 0);
    linear64<<<(N_ITEMS + 3) / 4, 256, 0, stream>>>(H1t, wt2T, bt2, s, N_ITEMS, 256, 1.0f, 1);
    linear64<<<(N_ITEMS + 3) / 4, 256, 0, stream>>>(s, wdT, bd, cur0 + (size_t)N_USERS * 64,
                                                    N_ITEMS, 64, 0.5f, 0);

    // ---- assemble ego, write out[:, 0:64] ----
    ego_fill<<<(N_NODES * EMB + 255) / 256, 256, 0, stream>>>(emb, cur0, out);

    // ---- propagation layer 1 (gather SpMM, no atomics) ----
    spmm_gather<<<(N_NODES + 3) / 4, 256, 0, stream>>>(row_ptr, col_s, val_s, cur0, nb);
    concat_lin<<<(N_NODES + 3) / 4, 256, 0, stream>>>(cur0, nb, wc0T, bc0, cur1, out, 64);

    // ---- propagation layer 2 ----
    spmm_gather<<<(N_NODES + 3) / 4, 256, 0, stream>>>(row_ptr, col_s, val_s, cur1, nb);
    concat_lin<<<(N_NODES + 3) / 4, 256, 0, stream>>>(cur1, nb, wc1T, bc1, nullptr, out, 128);
}